// Round 1
// baseline (1250.065 us; speedup 1.0000x reference)
//
#include <hip/hip_runtime.h>
#include <hip/hip_fp16.h>
#include <cstdint>

#define DEV static __device__ __forceinline__

typedef _Float16 h2v __attribute__((ext_vector_type(2)));

union U32H2 { uint32_t u; _Float16 f[2]; };

DEV uint32_t pack_f2(float a, float b) {
#if __has_builtin(__builtin_amdgcn_cvt_pkrtz)
    auto p = __builtin_amdgcn_cvt_pkrtz(a, b);
    return __builtin_bit_cast(uint32_t, p);
#else
    U32H2 c; c.f[0] = (_Float16)a; c.f[1] = (_Float16)b; return c.u;
#endif
}

DEV float dot2acc(uint32_t w, uint32_t h, float acc) {
#if __has_builtin(__builtin_amdgcn_fdot2)
    return __builtin_amdgcn_fdot2(__builtin_bit_cast(h2v, w),
                                  __builtin_bit_cast(h2v, h), acc, false);
#else
    U32H2 cw, ch; cw.u = w; ch.u = h;
    return acc + (float)cw.f[0]*(float)ch.f[0] + (float)cw.f[1]*(float)ch.f[1];
#endif
}

DEV float sigmoidf_(float x) { return 1.0f / (1.0f + __expf(-x)); }
DEV float tanh_fast(float x) { float e = __expf(-2.0f*x); return (1.0f - e) / (1.0f + e); }

// ---------------- workspace layout (uint32 units) ----------------
// N=384 H=256 Z=128 ED=128 AH=64
static const size_t OFF_W16T  = 0;          // 98304  : Whh as half2, [k2][o] transposed
static const size_t OFF_GI    = 98304;      // 768    : z@Wih.T + bih
static const size_t OFF_CC    = 99072;      // 128    : eg_b2 @ aW1[:128] (att0 | att1)
static const size_t OFF_W2AK  = 99200;      // 65536  : (eg_W2@[a0W1[:128]|a1W1[:128]]) packed pairs along K
static const size_t OFF_NODES = 164736;     // 98304  : GRU outputs fp32 [384][256]
static const size_t OFF_PH    = 263040;     // 196608 : (nodes@W1a + b1) half2 [384][512]
static const size_t OFF_QH    = 459648;     // 196608 : (nodes@W1b) half2 [384][512]
static const size_t OFF_R0    = 656256;     // 24576  : fp32 [384][64]
static const size_t OFF_R1    = 680832;     // 24576
static const size_t OFF_TT    = 705408;     // 9437184: T half2 [s][d][64 pairs] (j 0..63 att0, 64..127 att1)
static const size_t OFF_ATT0  = 10142592;   // 147456 : fp32 [s][d]
static const size_t OFF_ATT1  = 10290048;   // 147456
static const size_t OFF_AGG   = 10437504;   // 98304
static const size_t OFF_X0    = 10535808;   // 98304
static const size_t OFF_CS    = 10634112;   // 384
static const size_t OFF_V     = 10634496;   // 256
static const size_t WS_TOTAL  = 10634752;   // u32 elems (~42.5 MB)

// ---------------- prep kernels ----------------
__global__ void k_prep_w16(const float* __restrict__ Whh, uint32_t* __restrict__ W16T) {
    int idx = blockIdx.x * 256 + threadIdx.x;          // < 98304
    int k2 = idx / 768, o = idx - k2 * 768;
    W16T[idx] = pack_f2(Whh[o*256 + 2*k2], Whh[o*256 + 2*k2 + 1]);
}

__global__ void k_prep_gi(const float* __restrict__ z, const float* __restrict__ Wih,
                          const float* __restrict__ bih, float* __restrict__ gi) {
    int o = blockIdx.x * 256 + threadIdx.x;            // < 768
    float acc = bih[o];
    for (int i = 0; i < 128; ++i) acc += Wih[o*128 + i] * z[i];
    gi[o] = acc;
}

__global__ void k_prep_cc(const float* __restrict__ eg_b2, const float* __restrict__ a0W1,
                          const float* __restrict__ a1W1, float* __restrict__ cc) {
    int t = threadIdx.x;                               // < 128
    const float* A = (t < 64) ? a0W1 : a1W1;
    int j = t & 63;
    float acc = 0.f;
    for (int i = 0; i < 128; ++i) acc += eg_b2[i] * A[i*64 + j];
    cc[t] = acc;
}

__global__ void k_prep_w2a(const float* __restrict__ eg_W2, const float* __restrict__ a0W1,
                           const float* __restrict__ a1W1, uint32_t* __restrict__ W2AK) {
    int idx = blockIdx.x * 256 + threadIdx.x;          // < 65536
    int k2 = idx >> 7, j = idx & 127;
    const float* A = (j < 64) ? (a0W1 + j) : (a1W1 + (j - 64));
    const float* w0 = eg_W2 + (2*k2) * 128;
    float a = 0.f, b = 0.f;
    for (int i = 0; i < 128; ++i) {
        float av = A[i*64];
        a += w0[i] * av;
        b += w0[128 + i] * av;
    }
    W2AK[idx] = pack_f2(a, b);
}

// ---------------- GRU: 1 block, 768 threads, Whh(f16) register-resident ----------------
__global__ void __launch_bounds__(768, 3)
k_gru(const float* __restrict__ gi, const float* __restrict__ bhh,
      const uint32_t* __restrict__ W16T, float* __restrict__ nodes) {
    int tid = threadIdx.x;                             // 0..767 : one Whh row each
    __shared__ float hs[256];
    __shared__ __align__(16) uint32_t hh[128];
    __shared__ float ghs[768];
    __shared__ float gis[768];

    uint32_t w[128];
    #pragma unroll
    for (int k2 = 0; k2 < 128; ++k2) w[k2] = W16T[k2*768 + tid];
    float bh = bhh[tid];
    gis[tid] = gi[tid];
    if (tid < 256) hs[tid] = 0.f;
    if (tid < 128) hh[tid] = 0u;
    __syncthreads();

    for (int t = 0; t < 384; ++t) {
        float acc = bh;
        const uint4* hh4 = (const uint4*)hh;
        #pragma unroll
        for (int k8 = 0; k8 < 32; ++k8) {
            uint4 hv = hh4[k8];
            acc = dot2acc(w[4*k8+0], hv.x, acc);
            acc = dot2acc(w[4*k8+1], hv.y, acc);
            acc = dot2acc(w[4*k8+2], hv.z, acc);
            acc = dot2acc(w[4*k8+3], hv.w, acc);
        }
        ghs[tid] = acc;
        __syncthreads();
        if (tid < 128) {
            int i0 = 2*tid, i1 = i0 + 1;
            float r0 = sigmoidf_(gis[i0] + ghs[i0]);
            float r1 = sigmoidf_(gis[i1] + ghs[i1]);
            float u0 = sigmoidf_(gis[256+i0] + ghs[256+i0]);
            float u1 = sigmoidf_(gis[256+i1] + ghs[256+i1]);
            float n0 = tanh_fast(gis[512+i0] + r0*ghs[512+i0]);
            float n1 = tanh_fast(gis[512+i1] + r1*ghs[512+i1]);
            float h0 = (1.f - u0)*n0 + u0*hs[i0];
            float h1 = (1.f - u1)*n1 + u1*hs[i1];
            hs[i0] = h0; hs[i1] = h1;
            hh[tid] = pack_f2(h0, h1);
            ((float2*)nodes)[t*128 + tid] = make_float2(h0, h1);
        }
        __syncthreads();
    }
}

// ---------------- P, Q, R0 ----------------
__global__ void k_pq(const float* __restrict__ nodes, const float* __restrict__ eg_W1,
                     const float* __restrict__ eg_b1, const float* __restrict__ a0W1,
                     const float* __restrict__ a0b1, const float* __restrict__ cc,
                     uint32_t* __restrict__ Ph, uint32_t* __restrict__ Qh,
                     float* __restrict__ R0) {
    int tid = threadIdx.x;
    int s0 = blockIdx.x * 4;
    __shared__ float ns[4][256];
    #pragma unroll
    for (int q = 0; q < 4; ++q) ns[q][tid] = nodes[(s0+q)*256 + tid];
    __syncthreads();

    int k0 = tid * 4;
    float acc[4][4];
    #pragma unroll
    for (int q = 0; q < 4; ++q) { acc[q][0]=0;acc[q][1]=0;acc[q][2]=0;acc[q][3]=0; }
    for (int i = 0; i < 256; ++i) {
        float4 wv = *(const float4*)&eg_W1[i*1024 + k0];
        #pragma unroll
        for (int q = 0; q < 4; ++q) {
            float nv = ns[q][i];
            acc[q][0] += nv*wv.x; acc[q][1] += nv*wv.y;
            acc[q][2] += nv*wv.z; acc[q][3] += nv*wv.w;
        }
    }
    float4 bv = *(const float4*)&eg_b1[k0];
    #pragma unroll
    for (int q = 0; q < 4; ++q) {
        uint2 pw;
        pw.x = pack_f2(acc[q][0] + bv.x, acc[q][1] + bv.y);
        pw.y = pack_f2(acc[q][2] + bv.z, acc[q][3] + bv.w);
        ((uint2*)Ph)[(s0+q)*256 + tid] = pw;
    }

    #pragma unroll
    for (int q = 0; q < 4; ++q) { acc[q][0]=0;acc[q][1]=0;acc[q][2]=0;acc[q][3]=0; }
    for (int i = 0; i < 256; ++i) {
        float4 wv = *(const float4*)&eg_W1[(256+i)*1024 + k0];
        #pragma unroll
        for (int q = 0; q < 4; ++q) {
            float nv = ns[q][i];
            acc[q][0] += nv*wv.x; acc[q][1] += nv*wv.y;
            acc[q][2] += nv*wv.z; acc[q][3] += nv*wv.w;
        }
    }
    #pragma unroll
    for (int q = 0; q < 4; ++q) {
        uint2 pw;
        pw.x = pack_f2(acc[q][0], acc[q][1]);
        pw.y = pack_f2(acc[q][2], acc[q][3]);
        ((uint2*)Qh)[(s0+q)*256 + tid] = pw;
    }

    // R0 = nodes @ a0W1[128:384] + a0b1 + cc0
    int srow = tid >> 6, j = tid & 63;
    float racc = a0b1[j] + cc[j];
    for (int i = 0; i < 256; ++i) racc += ns[srow][i] * a0W1[(128+i)*64 + j];
    R0[(s0+srow)*64 + j] = racc;
}

// ---------------- phase A: T[s,d,0:128] = relu(P[s]+Q[d]) @ W2A ----------------
// grid (48, 24, 2), block 128: 8 s x 16 d per block, 64 of 128 j per block
__global__ void __launch_bounds__(128)
k_phaseA(const uint32_t* __restrict__ Ph, const uint32_t* __restrict__ Qh,
         const uint32_t* __restrict__ W2AK, uint32_t* __restrict__ TT) {
    int tid = threadIdx.x;
    int s0 = blockIdx.x * 8, d0 = blockIdx.y * 16, jb = blockIdx.z;
    int sl = tid >> 4, dl = tid & 15;
    __shared__ uint32_t PhS[8*33];
    __shared__ uint32_t QhS[16*33];
    __shared__ __align__(16) uint32_t WS[32*64];

    float acc[64];
    #pragma unroll
    for (int m = 0; m < 64; ++m) acc[m] = 0.f;

    for (int kc = 0; kc < 16; ++kc) {
        __syncthreads();
        for (int q = tid; q < 256; q += 128) { int r=q>>5, c=q&31; PhS[r*33+c] = Ph[(s0+r)*512 + kc*32 + c]; }
        for (int q = tid; q < 512; q += 128) { int r=q>>5, c=q&31; QhS[r*33+c] = Qh[(d0+r)*512 + kc*32 + c]; }
        for (int q = tid; q < 2048; q += 128) { int r=q>>6, c=q&63; WS[q] = W2AK[(kc*32+r)*128 + jb*64 + c]; }
        __syncthreads();

        for (int k2 = 0; k2 < 32; ++k2) {
            U32H2 cp, cq;
            cp.u = PhS[sl*33 + k2];
            cq.u = QhS[dl*33 + k2];
            float x0 = fmaxf((float)cp.f[0] + (float)cq.f[0], 0.f);
            float x1 = fmaxf((float)cp.f[1] + (float)cq.f[1], 0.f);
            uint32_t h1 = pack_f2(x0, x1);
            const uint4* w4 = (const uint4*)&WS[k2*64];
            #pragma unroll
            for (int jj = 0; jj < 16; ++jj) {
                uint4 wv = w4[jj];
                acc[4*jj+0] = dot2acc(wv.x, h1, acc[4*jj+0]);
                acc[4*jj+1] = dot2acc(wv.y, h1, acc[4*jj+1]);
                acc[4*jj+2] = dot2acc(wv.z, h1, acc[4*jj+2]);
                acc[4*jj+3] = dot2acc(wv.w, h1, acc[4*jj+3]);
            }
        }
    }

    int s = s0 + sl, d = d0 + dl;
    uint32_t* tt = TT + ((size_t)(s*384 + d))*64 + jb*32;
    #pragma unroll
    for (int m = 0; m < 8; ++m) {
        uint4 o;
        o.x = pack_f2(acc[8*m+0], acc[8*m+1]);
        o.y = pack_f2(acc[8*m+2], acc[8*m+3]);
        o.z = pack_f2(acc[8*m+4], acc[8*m+5]);
        o.w = pack_f2(acc[8*m+6], acc[8*m+7]);
        ((uint4*)tt)[m] = o;
    }
}

// ---------------- attention: ATT[s,d] = sigmoid(relu(T + R[s]) @ w2 + b2), diag = 0 ----------------
__global__ void k_att(const uint32_t* __restrict__ TT, const float* __restrict__ R,
                      const float* __restrict__ w2, const float* __restrict__ b2,
                      int off, float* __restrict__ ATT) {
    int p = blockIdx.x * 256 + threadIdx.x;            // < 147456
    int s = p / 384, d = p - s * 384;
    __shared__ float w2s[64];
    if (threadIdx.x < 64) w2s[threadIdx.x] = w2[threadIdx.x];
    __syncthreads();
    const uint4* tp = (const uint4*)(TT + (size_t)p*64 + off);
    const float* rp = R + s*64;
    float logit = b2[0];
    #pragma unroll
    for (int m = 0; m < 8; ++m) {
        uint4 tv = tp[m];
        uint32_t us[4] = {tv.x, tv.y, tv.z, tv.w};
        #pragma unroll
        for (int q = 0; q < 4; ++q) {
            U32H2 c; c.u = us[q];
            int j = m*8 + q*2;
            float h0 = fmaxf((float)c.f[0] + rp[j],   0.f);
            float h1 = fmaxf((float)c.f[1] + rp[j+1], 0.f);
            logit += h0*w2s[j] + h1*w2s[j+1];
        }
    }
    float a = 1.f / (1.f + __expf(-logit));
    ATT[p] = (s == d) ? 0.f : a;
}

// ---------------- agg[d] = sum_s ATT[s,d] * X[s] ----------------
__global__ void k_agg(const float* __restrict__ ATT, const float* __restrict__ X,
                      float* __restrict__ AGG) {
    int d = blockIdx.x, tid = threadIdx.x;
    float acc = 0.f;
    for (int s = 0; s < 384; s += 4) {
        float a0 = ATT[(s+0)*384 + d], a1 = ATT[(s+1)*384 + d];
        float a2 = ATT[(s+2)*384 + d], a3 = ATT[(s+3)*384 + d];
        acc += a0*X[(s+0)*256 + tid] + a1*X[(s+1)*256 + tid]
             + a2*X[(s+2)*256 + tid] + a3*X[(s+3)*256 + tid];
    }
    AGG[d*256 + tid] = acc;
}

// ---------------- x0 = relu(agg@W+b); R1 = x0 @ a1W1[128:] + a1b1 + cc1 ----------------
__global__ void k_x0r1(const float* __restrict__ AGG, const float* __restrict__ W,
                       const float* __restrict__ b, const float* __restrict__ a1W1,
                       const float* __restrict__ a1b1, const float* __restrict__ cc,
                       float* __restrict__ X0, float* __restrict__ R1) {
    int d = blockIdx.x, tid = threadIdx.x;
    __shared__ float ag[256];
    __shared__ float xs[256];
    ag[tid] = AGG[d*256 + tid];
    __syncthreads();
    float acc = b[tid];
    for (int i = 0; i < 256; ++i) acc += ag[i] * W[i*256 + tid];
    acc = fmaxf(acc, 0.f);
    X0[d*256 + tid] = acc;
    xs[tid] = acc;
    __syncthreads();
    if (tid < 64) {
        float r = a1b1[tid] + cc[64 + tid];
        for (int i = 0; i < 256; ++i) r += xs[i] * a1W1[(128+i)*64 + tid];
        R1[d*64 + tid] = r;
    }
}

__global__ void k_colsum(const float* __restrict__ ATT, float* __restrict__ CS) {
    int s = blockIdx.x, t = threadIdx.x;               // block 64
    float acc = 0.f;
    for (int d = t; d < 384; d += 64) acc += ATT[s*384 + d];
    for (int o = 32; o > 0; o >>= 1) acc += __shfl_down(acc, o, 64);
    if (t == 0) CS[s] = acc;
}

__global__ void k_v(const float* __restrict__ CS, const float* __restrict__ X0,
                    float* __restrict__ V) {
    int tid = threadIdx.x;
    __shared__ float cs[384];
    for (int q = tid; q < 384; q += 256) cs[q] = CS[q];
    __syncthreads();
    float acc = 0.f;
    for (int s = 0; s < 384; s += 4) {
        acc += cs[s]*X0[s*256 + tid] + cs[s+1]*X0[(s+1)*256 + tid]
             + cs[s+2]*X0[(s+2)*256 + tid] + cs[s+3]*X0[(s+3)*256 + tid];
    }
    V[tid] = acc;
}

__global__ void k_out(const float* __restrict__ V, const float* __restrict__ W,
                      const float* __restrict__ b, float* __restrict__ out) {
    int tid = threadIdx.x;
    __shared__ float vs[256];
    vs[tid] = V[tid];
    __syncthreads();
    float acc = 384.f * b[tid];
    for (int i = 0; i < 256; ++i) acc += vs[i] * W[i*256 + tid];
    out[tid] = acc;
}

extern "C" void kernel_launch(void* const* d_in, const int* in_sizes, int n_in,
                              void* d_out, int out_size, void* d_ws, size_t ws_size,
                              hipStream_t stream) {
    if (ws_size < WS_TOTAL * sizeof(uint32_t)) return;  // workspace too small -> fail loudly

    const float* z    = (const float*)d_in[0];
    const float* Wih  = (const float*)d_in[1];
    const float* Whh  = (const float*)d_in[2];
    const float* bih  = (const float*)d_in[3];
    const float* bhh  = (const float*)d_in[4];
    const float* egW1 = (const float*)d_in[5];
    const float* egb1 = (const float*)d_in[6];
    const float* egW2 = (const float*)d_in[7];
    const float* egb2 = (const float*)d_in[8];
    const float* a0W1 = (const float*)d_in[9];
    const float* a0b1 = (const float*)d_in[10];
    const float* a0W2 = (const float*)d_in[11];
    const float* a0b2 = (const float*)d_in[12];
    const float* a1W1 = (const float*)d_in[13];
    const float* a1b1 = (const float*)d_in[14];
    const float* a1W2 = (const float*)d_in[15];
    const float* a1b2 = (const float*)d_in[16];
    const float* c0W  = (const float*)d_in[17];
    const float* c0b  = (const float*)d_in[18];
    const float* c1W  = (const float*)d_in[19];
    const float* c1b  = (const float*)d_in[20];

    uint32_t* ws   = (uint32_t*)d_ws;
    uint32_t* W16T = ws + OFF_W16T;
    float*    gi   = (float*)(ws + OFF_GI);
    float*    cc   = (float*)(ws + OFF_CC);
    uint32_t* W2AK = ws + OFF_W2AK;
    float*    nodes= (float*)(ws + OFF_NODES);
    uint32_t* Ph   = ws + OFF_PH;
    uint32_t* Qh   = ws + OFF_QH;
    float*    R0   = (float*)(ws + OFF_R0);
    float*    R1   = (float*)(ws + OFF_R1);
    uint32_t* TT   = ws + OFF_TT;
    float*    ATT0 = (float*)(ws + OFF_ATT0);
    float*    ATT1 = (float*)(ws + OFF_ATT1);
    float*    AGG  = (float*)(ws + OFF_AGG);
    float*    X0   = (float*)(ws + OFF_X0);
    float*    CS   = (float*)(ws + OFF_CS);
    float*    V    = (float*)(ws + OFF_V);
    float*    out  = (float*)d_out;

    hipLaunchKernelGGL(k_prep_w16, dim3(384), dim3(256), 0, stream, Whh, W16T);
    hipLaunchKernelGGL(k_prep_gi,  dim3(3),   dim3(256), 0, stream, z, Wih, bih, gi);
    hipLaunchKernelGGL(k_prep_cc,  dim3(1),   dim3(128), 0, stream, egb2, a0W1, a1W1, cc);
    hipLaunchKernelGGL(k_prep_w2a, dim3(256), dim3(256), 0, stream, egW2, a0W1, a1W1, W2AK);
    hipLaunchKernelGGL(k_gru,      dim3(1),   dim3(768), 0, stream, gi, bhh, W16T, nodes);
    hipLaunchKernelGGL(k_pq,       dim3(96),  dim3(256), 0, stream, nodes, egW1, egb1, a0W1, a0b1, cc, Ph, Qh, R0);
    hipLaunchKernelGGL(k_phaseA,   dim3(48, 24, 2), dim3(128), 0, stream, Ph, Qh, W2AK, TT);
    hipLaunchKernelGGL(k_att,      dim3(576), dim3(256), 0, stream, TT, R0, a0W2, a0b2, 0,  ATT0);
    hipLaunchKernelGGL(k_agg,      dim3(384), dim3(256), 0, stream, ATT0, nodes, AGG);
    hipLaunchKernelGGL(k_x0r1,     dim3(384), dim3(256), 0, stream, AGG, c0W, c0b, a1W1, a1b1, cc, X0, R1);
    hipLaunchKernelGGL(k_att,      dim3(576), dim3(256), 0, stream, TT, R1, a1W2, a1b2, 32, ATT1);
    hipLaunchKernelGGL(k_colsum,   dim3(384), dim3(64),  0, stream, ATT1, CS);
    hipLaunchKernelGGL(k_v,        dim3(1),   dim3(256), 0, stream, CS, X0, V);
    hipLaunchKernelGGL(k_out,      dim3(1),   dim3(256), 0, stream, V, c1W, c1b, out);
}